// Round 1
// baseline (180.085 us; speedup 1.0000x reference)
//
#include <hip/hip_runtime.h>
#include <hip/hip_bf16.h>
#include <math.h>

// Problem constants
#define BZ      64
#define NC      2048
#define HH      14
#define HW      196        // 14*14
#define NCLS    1000
#define SPLITS  8
#define CPB     (NC/SPLITS)   // 256 channels per block
#define CHUNK   8
#define NCHUNK  (CPB/CHUNK)   // 32

// ws layout (floats)
#define CAM_OFF  0                                  // [64][8][3][196]
#define G_OFF    (BZ*SPLITS*3*HW)                   // 301056, [64][8][196]
#define S_OFF    (G_OFF + BZ*SPLITS*HW)             // 401408, [64][8][14]
#define TERM_OFF (S_OFF + BZ*SPLITS*HH)             // 408576, [64]

// ---------------------------------------------------------------------------
// Kernel 1: per (batch, channel-split) compute raw-CAM partials (3x196),
// Gram partial G[14][14], and row-sum partial S[14].
// Wave 0 (t<49): cam + S, float4 LDS reads.  Waves 1-4 (64<=t<288): Gram via
// 2x2 upper-triangle tiles (28 tiles x 8 channel groups).
// ---------------------------------------------------------------------------
__global__ __launch_bounds__(320) void k_stage1(
    const float* __restrict__ F, const float* __restrict__ W,
    const int* __restrict__ idx, float* __restrict__ ws)
{
  __shared__ __align__(16) float Fs[2][CHUNK*HW];   // 2 x 1568
  __shared__ __align__(16) float wls[3][CPB];
  __shared__ __align__(16) float sred[HW];
  __shared__ __align__(16) float gred[224*4];

  const int t = threadIdx.x;
  const int s = blockIdx.x;     // split
  const int b = blockIdx.y;     // batch
  const int cbase = s*CPB;

  const int i0 = idx[b*3+0], i1 = idx[b*3+1], i2 = idx[b*3+2];
  if (t < CPB){
    wls[0][t] = W[(size_t)i0*NC + cbase + t];
    wls[1][t] = W[(size_t)i1*NC + cbase + t];
    wls[2][t] = W[(size_t)i2*NC + cbase + t];
  }

  const float* Fb = F + ((size_t)b*NC + cbase)*HW;

  const bool isCam = (t < 49);
  const bool isG   = (t >= 64 && t < 288);
  int m0=0,m1=0,n0=0,n1=0, cg=0, tmKeep=0, tnKeep=0;
  if (isG){
    int g = t - 64;
    int tile = g % 28; cg = g / 28;       // 28 tiles, 8 channel groups
    int k = tile, tm = 0;
    while (k >= 7 - tm){ k -= 7 - tm; tm++; }
    int tn = tm + k;
    tmKeep = tm; tnKeep = tn;
    m0 = 2*tm; m1 = m0+1; n0 = 2*tn; n1 = n0+1;
  }
  (void)tmKeep; (void)tnKeep;

  float4 c0a = make_float4(0.f,0.f,0.f,0.f);
  float4 c1a = make_float4(0.f,0.f,0.f,0.f);
  float4 c2a = make_float4(0.f,0.f,0.f,0.f);
  float4 sA  = make_float4(0.f,0.f,0.f,0.f);
  float g00=0.f, g01=0.f, g10=0.f, g11=0.f;

  float4 pre0 = make_float4(0.f,0.f,0.f,0.f);
  float4 pre1 = make_float4(0.f,0.f,0.f,0.f);

  auto loadChunk = [&](int ch){
    if (t < 196){
      const float4* src = (const float4*)(Fb + (size_t)ch*CHUNK*HW);
      pre0 = src[2*t]; pre1 = src[2*t+1];
    }
  };
  auto storeChunk = [&](int bufi){
    if (t < 196){
      float4* dst = (float4*)(&Fs[bufi][0]);
      dst[2*t] = pre0; dst[2*t+1] = pre1;
    }
  };

  loadChunk(0);
  storeChunk(0);
  __syncthreads();

  for (int ch = 0; ch < NCHUNK; ++ch){
    const int bufi = ch & 1;
    if (ch+1 < NCHUNK) loadChunk(ch+1);   // prefetch next slab into regs
    const float* Fsb = &Fs[bufi][0];

    if (isCam){
      float w0a[CHUNK], w1a[CHUNK], w2a[CHUNK];
      *(float4*)&w0a[0] = *(const float4*)&wls[0][ch*CHUNK];
      *(float4*)&w0a[4] = *(const float4*)&wls[0][ch*CHUNK+4];
      *(float4*)&w1a[0] = *(const float4*)&wls[1][ch*CHUNK];
      *(float4*)&w1a[4] = *(const float4*)&wls[1][ch*CHUNK+4];
      *(float4*)&w2a[0] = *(const float4*)&wls[2][ch*CHUNK];
      *(float4*)&w2a[4] = *(const float4*)&wls[2][ch*CHUNK+4];
      #pragma unroll
      for (int c=0;c<CHUNK;c++){
        float4 v = *(const float4*)(Fsb + c*HW + 4*t);
        c0a.x += w0a[c]*v.x; c0a.y += w0a[c]*v.y; c0a.z += w0a[c]*v.z; c0a.w += w0a[c]*v.w;
        c1a.x += w1a[c]*v.x; c1a.y += w1a[c]*v.y; c1a.z += w1a[c]*v.z; c1a.w += w1a[c]*v.w;
        c2a.x += w2a[c]*v.x; c2a.y += w2a[c]*v.y; c2a.z += w2a[c]*v.z; c2a.w += w2a[c]*v.w;
        sA.x += v.x; sA.y += v.y; sA.z += v.z; sA.w += v.w;
      }
    }
    if (isG){
      const float* Mb = Fsb + cg*HW;
      const float2* r0 = (const float2*)(Mb + m0*HH);
      const float2* r1 = (const float2*)(Mb + m1*HH);
      const float2* q0 = (const float2*)(Mb + n0*HH);
      const float2* q1 = (const float2*)(Mb + n1*HH);
      #pragma unroll
      for (int jj=0;jj<7;jj++){
        float2 a0=r0[jj], a1=r1[jj], b0=q0[jj], b1=q1[jj];
        g00 += a0.x*b0.x + a0.y*b0.y;
        g01 += a0.x*b1.x + a0.y*b1.y;
        g10 += a1.x*b0.x + a1.y*b0.y;
        g11 += a1.x*b1.x + a1.y*b1.y;
      }
    }
    if (ch+1 < NCHUNK) storeChunk((ch+1)&1);
    __syncthreads();
  }

  // ---- epilogue ----
  const size_t pslot = (size_t)(b*SPLITS + s);
  if (isCam){
    float* base = ws + CAM_OFF + pslot*3*HW;
    *(float4*)(base          + 4*t) = c0a;
    *(float4*)(base + HW     + 4*t) = c1a;
    *(float4*)(base + 2*HW   + 4*t) = c2a;
    *(float4*)(sred + 4*t) = sA;
  }
  if (isG){
    int g = t - 64;
    float* gr = &gred[g*4];
    gr[0]=g00; gr[1]=g01; gr[2]=g10; gr[3]=g11;
  }
  __syncthreads();

  if (t < HH){
    float acc=0.f;
    #pragma unroll
    for (int j=0;j<HH;j++) acc += sred[t*HH+j];
    ws[S_OFF + pslot*HH + t] = acc;
  }
  if (t < 112){
    int tile = t >> 2, q = t & 3;
    int k = tile, tm2 = 0;
    while (k >= 7 - tm2){ k -= 7 - tm2; tm2++; }
    int tn2 = tm2 + k;
    float acc=0.f;
    #pragma unroll
    for (int c=0;c<8;c++) acc += gred[(c*28+tile)*4 + q];
    int a = q>>1, bb = q&1;
    int mm = 2*tm2 + a, nn = 2*tn2 + bb;
    float* gb = ws + G_OFF + pslot*HW;
    gb[mm*HH+nn] = acc;
    if (tn2 > tm2) gb[nn*HH+mm] = acc;
  }
}

// ---------------------------------------------------------------------------
// block reduce: MODE 0=sum, 1=min, 2=max; result broadcast to all 256 threads
// ---------------------------------------------------------------------------
template<int MODE>
__device__ __forceinline__ float bred(float v, float* red){
  #pragma unroll
  for (int o=32;o>0;o>>=1){
    float u = __shfl_down(v, o, 64);
    if (MODE==0) v += u; else if (MODE==1) v = fminf(v,u); else v = fmaxf(v,u);
  }
  __syncthreads();
  if ((threadIdx.x & 63)==0) red[threadIdx.x>>6] = v;
  __syncthreads();
  float r = red[0];
  #pragma unroll
  for (int w=1;w<4;w++){
    float u = red[w];
    if (MODE==0) r += u; else if (MODE==1) r = fminf(r,u); else r = fmaxf(r,u);
  }
  return r;
}

// ---------------------------------------------------------------------------
// Kernel 2: per-batch — reduce partials, normalize cams, dst/ed1, quadratic
// forms for d01/d02, cross-entropy, per-batch term.
// ---------------------------------------------------------------------------
__global__ __launch_bounds__(256) void k_stage2(
    const float* __restrict__ pred, const int* __restrict__ cla,
    const float* __restrict__ seg, float* __restrict__ ws)
{
  const int t = threadIdx.x, b = blockIdx.x;
  __shared__ float cam[3][HW], Gm[HW], Sv[HH];
  __shared__ float D1[HW], D2[HW], EE[HW];
  __shared__ float rowv[HH], dc1[HH], dc2[HH];
  __shared__ float red[4];
  __shared__ float scal[6];

  // A: reduce split partials
  if (t < HW){
    for (int k=0;k<3;k++){
      float a=0.f;
      for (int s=0;s<SPLITS;s++)
        a += ws[CAM_OFF + ((size_t)(b*SPLITS+s)*3 + k)*HW + t];
      cam[k][t]=a;
    }
    float g=0.f;
    for (int s=0;s<SPLITS;s++) g += ws[G_OFF + (size_t)(b*SPLITS+s)*HW + t];
    Gm[t]=g;
  }
  if (t < HH){
    float a=0.f;
    for (int s=0;s<SPLITS;s++) a += ws[S_OFF + (size_t)(b*SPLITS+s)*HH + t];
    Sv[t]=a;
  }
  __syncthreads();

  // B: per-cam min/max
  for (int k=0;k<3;k++){
    float v = (t<HW)? cam[k][t] : 3.0e38f;
    float mn = bred<1>(v, red);
    v = (t<HW)? cam[k][t] : -3.0e38f;
    float mx = bred<2>(v, red);
    if (t==0){ scal[2*k]=mn; scal[2*k+1]=mx; }
  }
  __syncthreads();

  // C: normalize (matches ref: (x-mn)/max(x-mn) * 255), dst, D, EE
  if (t < HW){
    float c0 = (cam[0][t]-scal[0]) / (scal[1]-scal[0]) * 255.0f;
    float c1 = (cam[1][t]-scal[2]) / (scal[3]-scal[2]) * 255.0f;
    float c2 = (cam[2][t]-scal[4]) / (scal[5]-scal[4]) * 255.0f;
    float dst = (c0 > 125.0f) ? 1.0f : 0.0f;
    D1[t] = c0 - c1; D2[t] = c0 - c2;
    float e = dst - seg[(size_t)b*HW + t] + 1e-6f;
    EE[t] = e*e;
  }
  __syncthreads();

  if (t < HH){
    float rs=0.f, d1=0.f, d2=0.f;
    #pragma unroll
    for (int j=0;j<HH;j++){
      rs += EE[t*HH+j];
      d1 += D1[j*HH+t];       // column sums of D
      d2 += D2[j*HH+t];
    }
    rowv[t] = sqrtf(rs); dc1[t]=d1; dc2[t]=d2;
  }
  __syncthreads();

  // D: H[m,m'] * G[m,m'] summed
  float v1=0.f, v2=0.f;
  if (t < HW){
    int m = t/HH, mp = t%HH;
    float h1=0.f, h2=0.f;
    #pragma unroll
    for (int i=0;i<HH;i++){
      h1 += D1[i*HH+m]*D1[i*HH+mp];
      h2 += D2[i*HH+m]*D2[i*HH+mp];
    }
    v1 = h1*Gm[t]; v2 = h2*Gm[t];
  }
  float sx2_1 = bred<0>(v1, red);
  float sx2_2 = bred<0>(v2, red);

  // E: logsumexp cross-entropy
  const float* pb = pred + (size_t)b*NCLS;
  float mv = -3.0e38f;
  for (int i=t;i<NCLS;i+=256) mv = fmaxf(mv, pb[i]);
  mv = bred<2>(mv, red);
  float es = 0.f;
  for (int i=t;i<NCLS;i+=256) es += expf(pb[i]-mv);
  es = bred<0>(es, red);

  if (t==0){
    float lse = mv + logf(es);
    float ce  = lse - pb[cla[b]];
    float ed1 = 0.f;
    #pragma unroll
    for (int i=0;i<HH;i++) ed1 += rowv[i];
    ed1 *= (1.0f/14.0f);
    float sx1=0.f, sx2=0.f;
    #pragma unroll
    for (int m=0;m<HH;m++){ sx1 += dc1[m]*Sv[m]; sx2 += dc2[m]*Sv[m]; }
    const float NEPS2 = 401408.0f * 1e-12f;
    float d01 = sqrtf(sx2_1 + 2e-6f*sx1 + NEPS2) * (1.0f/2048.0f);
    float d02 = sqrtf(sx2_2 + 2e-6f*sx2 + NEPS2) * (1.0f/2048.0f);
    float term = ed1 + fmaxf(0.0f, 70.0f - d01 - d02) + ce;
    ws[TERM_OFF + b] = term;
  }
}

// ---------------------------------------------------------------------------
// Kernel 3: mean over 64 batch terms -> scalar
// ---------------------------------------------------------------------------
__global__ void k_stage3(const float* __restrict__ ws, float* __restrict__ out){
  float v = ws[TERM_OFF + threadIdx.x];
  #pragma unroll
  for (int o=32;o>0;o>>=1) v += __shfl_down(v, o, 64);
  if (threadIdx.x==0) out[0] = v * (1.0f/64.0f);
}

extern "C" void kernel_launch(void* const* d_in, const int* in_sizes, int n_in,
                              void* d_out, int out_size, void* d_ws, size_t ws_size,
                              hipStream_t stream) {
  const float* pred = (const float*)d_in[0];
  const int*   cla  = (const int*)  d_in[1];
  const float* seg  = (const float*)d_in[2];
  const float* F    = (const float*)d_in[3];
  const float* W    = (const float*)d_in[4];
  const int*   idx  = (const int*)  d_in[5];
  float* out = (float*)d_out;
  float* ws  = (float*)d_ws;

  dim3 g1(SPLITS, BZ);
  k_stage1<<<g1, 320, 0, stream>>>(F, W, idx, ws);
  k_stage2<<<BZ, 256, 0, stream>>>(pred, cla, seg, ws);
  k_stage3<<<1, 64, 0, stream>>>(ws, out);
}